// Round 1
// baseline (452.446 us; speedup 1.0000x reference)
//
#include <hip/hip_runtime.h>

// Sobel conv (cross-correlation, zero-pad SAME) + sign-difference maps.
// x: [16,1,1024,1024] f32 -> y: [16,2,1024,1024], y0,y1: [16,1,1023,1023]
// Outputs concatenated flat in d_out (float32).
//
// Accumulate in double: weights are {1,2} integers so products are exact;
// f64 sum error ~1e-15 => sign() matches a float64 numpy reference always.

__device__ __forceinline__ double ldx(const float* __restrict__ xb, int r, int c) {
    // zero-padded load from one 1024x1024 image
    bool ok = ((unsigned)r < 1024u) && ((unsigned)c < 1024u);
    return ok ? (double)xb[(r << 10) | c] : 0.0;
}

__device__ __forceinline__ float fsign(double v) {
    return (v > 0.0) ? 1.0f : ((v < 0.0) ? -1.0f : 0.0f);
}

__global__ __launch_bounds__(256) void sobel_sign_kernel(const float* __restrict__ x,
                                                         float* __restrict__ out) {
    int idx = blockIdx.x * 256 + threadIdx.x;
    int b   = idx >> 20;          // image index (16)
    int rem = idx & 0xFFFFF;
    int h   = rem >> 10;          // row
    int w   = rem & 1023;         // col
    const float* xb = x + ((size_t)b << 20);

    // Neighborhood rows h-1..h+2, cols w-1..w+2 (15 values needed)
    double a00 = ldx(xb, h - 1, w - 1), a01 = ldx(xb, h - 1, w);
    double a02 = ldx(xb, h - 1, w + 1), a03 = ldx(xb, h - 1, w + 2);
    double a10 = ldx(xb, h,     w - 1), a11 = ldx(xb, h,     w);
    double a12 = ldx(xb, h,     w + 1), a13 = ldx(xb, h,     w + 2);
    double a20 = ldx(xb, h + 1, w - 1), a21 = ldx(xb, h + 1, w);
    double a22 = ldx(xb, h + 1, w + 1), a23 = ldx(xb, h + 1, w + 2);
    double a30 = ldx(xb, h + 2, w - 1), a31 = ldx(xb, h + 2, w);
    double a32 = ldx(xb, h + 2, w + 1);

    // Separable Sobel (cross-correlation):
    // gx(h,w) = t(w-1) - t(w+1),  t(c) = x(h-1,c) + 2x(h,c) + x(h+1,c)
    // gy(h,w) = d(w-1) + 2d(w) + d(w+1),  d(c) = x(h-1,c) - x(h+1,c)
    double t0 = a00 + 2.0 * a10 + a20;
    double t1 = a01 + 2.0 * a11 + a21;
    double t2 = a02 + 2.0 * a12 + a22;
    double t3 = a03 + 2.0 * a13 + a23;
    double gx00 = t0 - t2;   // gx at (h, w)
    double gx01 = t1 - t3;   // gx at (h, w+1)

    double d0 = a00 - a20, d1 = a01 - a21, d2 = a02 - a22;
    double gy00 = d0 + 2.0 * d1 + d2;                   // gy at (h, w)
    double e0 = a10 - a30, e1 = a11 - a31, e2 = a12 - a32;
    double gy10 = e0 + 2.0 * e1 + e2;                   // gy at (h+1, w)

    // y: [b, ch, h, w], ch0 = gx, ch1 = gy
    size_t ybase = ((size_t)b << 21);
    int hw = (h << 10) | w;
    out[ybase + hw]             = (float)gx00;
    out[ybase + (1 << 20) + hw] = (float)gy00;

    // y0[b,h,w] = sign(gx(h,w)) - sign(gx(h,w+1))  for h,w < 1023
    // y1[b,h,w] = sign(gy(h,w)) - sign(gy(h+1,w))
    if (h < 1023 && w < 1023) {
        const size_t NP = (size_t)1023 * 1023;        // 1046529
        size_t p = (size_t)b * NP + (size_t)h * 1023 + (size_t)w;
        out[33554432u + p] = fsign(gx00) - fsign(gx01);   // y0 base = 16*2*1024*1024
        out[50298896u + p] = fsign(gy00) - fsign(gy10);   // y1 base = +16*1023*1023
    }
}

extern "C" void kernel_launch(void* const* d_in, const int* in_sizes, int n_in,
                              void* d_out, int out_size, void* d_ws, size_t ws_size,
                              hipStream_t stream) {
    const float* x = (const float*)d_in[0];
    float* out = (float*)d_out;
    // 16 * 1024 * 1024 threads, 1 pixel each
    dim3 grid(65536), block(256);
    sobel_sign_kernel<<<grid, block, 0, stream>>>(x, out);
}

// Round 2
// 364.285 us; speedup vs baseline: 1.2420x; 1.2420x over previous
//
#include <hip/hip_runtime.h>

// Sobel conv (cross-correlation, zero-pad SAME) + sign-difference maps.
// x: [16,1,1024,1024] f32 -> y: [16,2,1024,1024], y0,y1: [16,1,1023,1023]
// Outputs concatenated flat in d_out (float32).
//
// f64 accumulation: weights {1,2} are exact, so sign() matches the true sign
// (round-1 passed with this; numerics unchanged).
//
// Layout: one block per (b, h) output row; 256 threads x 4 cols each.
// All loads unconditional (clamped addresses); boundary zeroing via value
// selects -> no per-load exec-mask branching.

struct Row7 { double v[7]; };  // cols w0-1 .. w0+5 for one input row

__device__ __forceinline__ Row7 load_row(const float* __restrict__ xb, int r, int t) {
    Row7 o;
    int rc = min(max(r, 0), 1023);
    float m = ((unsigned)r < 1024u) ? 1.0f : 0.0f;   // zero-pad rows
    const float4* __restrict__ rp = (const float4*)(xb + (rc << 10));
    float4 L = rp[(t > 0) ? (t - 1) : 0];
    float4 C = rp[t];
    float4 R = rp[(t < 255) ? (t + 1) : 255];
    float lw = (t > 0)   ? L.w : 0.0f;   // col w0-1 (zero-pad col -1)
    float r0 = (t < 255) ? R.x : 0.0f;   // col w0+4 (zero-pad col 1024)
    float r1 = (t < 255) ? R.y : 0.0f;   // col w0+5
    o.v[0] = (double)(lw  * m);
    o.v[1] = (double)(C.x * m);
    o.v[2] = (double)(C.y * m);
    o.v[3] = (double)(C.z * m);
    o.v[4] = (double)(C.w * m);
    o.v[5] = (double)(r0  * m);
    o.v[6] = (double)(r1  * m);
    return o;
}

__device__ __forceinline__ float fsign(double v) {
    return (v > 0.0) ? 1.0f : ((v < 0.0) ? -1.0f : 0.0f);
}

__global__ __launch_bounds__(256) void sobel_sign_kernel(const float* __restrict__ x,
                                                         float* __restrict__ out) {
    const int t  = threadIdx.x;        // 0..255 -> cols 4t..4t+3
    const int bh = blockIdx.x;         // b*1024 + h
    const int b  = bh >> 10;
    const int h  = bh & 1023;
    const int w0 = t << 2;
    const float* __restrict__ xb = x + ((size_t)b << 20);

    // Rows h-1, h, h+1 -> column sums tc and differences d; then row h+2 -> e.
    Row7 A0 = load_row(xb, h - 1, t);
    Row7 A1 = load_row(xb, h,     t);
    Row7 A2 = load_row(xb, h + 1, t);

    double tc[7], d[6];
    #pragma unroll
    for (int c = 0; c < 7; ++c) tc[c] = A0.v[c] + 2.0 * A1.v[c] + A2.v[c];
    #pragma unroll
    for (int c = 0; c < 6; ++c) d[c] = A0.v[c] - A2.v[c];

    Row7 A3 = load_row(xb, h + 2, t);
    double e[6];
    #pragma unroll
    for (int c = 0; c < 6; ++c) e[c] = A1.v[c] - A3.v[c];

    // Relative index: col = w0 - 1 + c.
    // gx(h,W)   = tc(W-1) - tc(W+1);  gy(h,W)   = d(W-1) + 2 d(W) + d(W+1)
    // gy(h+1,W) = e(W-1) + 2 e(W) + e(W+1)
    double gx0[4], gx1[4], gy0[4], gy1[4];
    #pragma unroll
    for (int j = 0; j < 4; ++j) {
        gx0[j] = tc[j]     - tc[j + 2];          // gx at (h, w0+j)
        gx1[j] = tc[j + 1] - tc[j + 3];          // gx at (h, w0+j+1)
        gy0[j] = d[j] + 2.0 * d[j + 1] + d[j + 2];   // gy at (h,   w0+j)
        gy1[j] = e[j] + 2.0 * e[j + 1] + e[j + 2];   // gy at (h+1, w0+j)
    }

    // y stores: [b, ch, h, w], float4-aligned
    float4 vgx = make_float4((float)gx0[0], (float)gx0[1], (float)gx0[2], (float)gx0[3]);
    float4 vgy = make_float4((float)gy0[0], (float)gy0[1], (float)gy0[2], (float)gy0[3]);
    size_t ybase = ((size_t)b << 21) + ((size_t)h << 10) + (size_t)w0;
    *(float4*)(out + ybase)               = vgx;
    *(float4*)(out + ybase + (1u << 20))  = vgy;

    // y0[b,h,w] = sign(gx(h,w)) - sign(gx(h,w+1));  y1 = sign(gy(h,w)) - sign(gy(h+1,w))
    if (h < 1023) {
        const size_t NP = (size_t)1023 * 1023;          // 1046529
        size_t p = (size_t)33554432u + (size_t)b * NP + (size_t)h * 1023u + (size_t)w0;
        #pragma unroll
        for (int j = 0; j < 4; ++j) {
            if (w0 + j < 1023) {
                out[p + j]             = fsign(gx0[j]) - fsign(gx1[j]);
                out[p + j + 16744464u] = fsign(gy0[j]) - fsign(gy1[j]);
            }
        }
    }
}

extern "C" void kernel_launch(void* const* d_in, const int* in_sizes, int n_in,
                              void* d_out, int out_size, void* d_ws, size_t ws_size,
                              hipStream_t stream) {
    const float* x = (const float*)d_in[0];
    float* out = (float*)d_out;
    dim3 grid(16 * 1024), block(256);   // one block per (b, h) row
    sobel_sign_kernel<<<grid, block, 0, stream>>>(x, out);
}

// Round 3
// 354.690 us; speedup vs baseline: 1.2756x; 1.0271x over previous
//
#include <hip/hip_runtime.h>

// Sobel conv (cross-correlation, zero-pad SAME) + sign-difference maps.
// x: [16,1,1024,1024] f32 -> y: [16,2,1024,1024], y0,y1: [16,1,1023,1023]
// Outputs concatenated flat in d_out (float32).
//
// f64 accumulation (weights {1,2} exact; sign() matches high-precision ref —
// passed rounds 1-2, numerics unchanged).
//
// Row-rolling: each thread owns 4 cols x 8 output rows. A 3-row f64 register
// window gives 4x load reuse; gy(h+1) for y1 is just next iteration's gy
// (emitted one row late via saved signs), gx(h,w+1) is in-thread.

__device__ __forceinline__ void load_row(const float* __restrict__ xb, int r, int t,
                                         double* __restrict__ o /*[7]*/) {
    int rc = min(max(r, 0), 1023);
    float m = ((unsigned)r < 1024u) ? 1.0f : 0.0f;   // zero-pad rows
    const float4* __restrict__ rp = (const float4*)(xb + (rc << 10));
    float4 L = rp[(t > 0) ? (t - 1) : 0];
    float4 C = rp[t];
    float4 R = rp[(t < 255) ? (t + 1) : 255];
    float lw = (t > 0)   ? L.w : 0.0f;   // col w0-1
    float r0 = (t < 255) ? R.x : 0.0f;   // col w0+4
    float r1 = (t < 255) ? R.y : 0.0f;   // col w0+5
    o[0] = (double)(lw  * m);
    o[1] = (double)(C.x * m);
    o[2] = (double)(C.y * m);
    o[3] = (double)(C.z * m);
    o[4] = (double)(C.w * m);
    o[5] = (double)(r0  * m);
    o[6] = (double)(r1  * m);
}

__device__ __forceinline__ float fsign(double v) {
    return (v > 0.0) ? 1.0f : ((v < 0.0) ? -1.0f : 0.0f);
}

__global__ __launch_bounds__(256) void sobel_sign_kernel(const float* __restrict__ x,
                                                         float* __restrict__ out) {
    const int t  = threadIdx.x;          // 0..255 -> cols 4t..4t+3
    const int b  = blockIdx.x >> 7;      // image
    const int hg = blockIdx.x & 127;     // row group
    const int h0 = hg << 3;              // first output row of this thread
    const int w0 = t << 2;

    const float* __restrict__ xb = x + ((size_t)b << 20);
    float* __restrict__ yb = out + ((size_t)b << 21);
    const size_t NP    = (size_t)1023 * 1023;      // 1046529
    const size_t Y0    = 33554432u + (size_t)b * NP;
    const size_t Y1    = 50298896u + (size_t)b * NP;

    double r[3][7];                      // rolling rows h-1, h, h+1
    load_row(xb, h0 - 1, t, r[0]);
    load_row(xb, h0,     t, r[1]);

    float psgy[4];                       // sign(gy) of previous row

    #pragma unroll
    for (int it = 0; it < 8; ++it) {
        const int h = h0 + it;
        double* A0 = r[it % 3];          // row h-1
        double* A1 = r[(it + 1) % 3];    // row h
        double* A2 = r[(it + 2) % 3];    // row h+1 (fresh load)
        load_row(xb, h + 1, t, A2);

        double tc[7], d[6];
        #pragma unroll
        for (int c = 0; c < 7; ++c) tc[c] = A0[c] + 2.0 * A1[c] + A2[c];
        #pragma unroll
        for (int c = 0; c < 6; ++c) d[c] = A0[c] - A2[c];

        double gx[5];                    // gx at (h, w0-? ) : cols w0..w0+4
        #pragma unroll
        for (int j = 0; j < 5; ++j) gx[j] = tc[j] - tc[j + 2];
        double gy[4];                    // gy at (h, w0..w0+3)
        #pragma unroll
        for (int j = 0; j < 4; ++j) gy[j] = d[j] + 2.0 * d[j + 1] + d[j + 2];

        // y stores (float4-aligned)
        size_t yo = ((size_t)h << 10) + (size_t)w0;
        *(float4*)(yb + yo) =
            make_float4((float)gx[0], (float)gx[1], (float)gx[2], (float)gx[3]);
        *(float4*)(yb + yo + (1u << 20)) =
            make_float4((float)gy[0], (float)gy[1], (float)gy[2], (float)gy[3]);

        float sgx[5], sgy[4];
        #pragma unroll
        for (int j = 0; j < 5; ++j) sgx[j] = fsign(gx[j]);
        #pragma unroll
        for (int j = 0; j < 4; ++j) sgy[j] = fsign(gy[j]);

        // y0[h,w] = sign(gx(h,w)) - sign(gx(h,w+1))
        if (h < 1023) {
            size_t p = Y0 + (size_t)h * 1023u + (size_t)w0;
            #pragma unroll
            for (int j = 0; j < 4; ++j)
                if (w0 + j < 1023) out[p + j] = sgx[j] - sgx[j + 1];
        }
        // y1[h-1,w] = sign(gy(h-1,w)) - sign(gy(h,w))
        if (it > 0) {
            size_t p = Y1 + (size_t)(h - 1) * 1023u + (size_t)w0;
            #pragma unroll
            for (int j = 0; j < 4; ++j)
                if (w0 + j < 1023) out[p + j] = psgy[j] - sgy[j];
        }
        #pragma unroll
        for (int j = 0; j < 4; ++j) psgy[j] = sgy[j];
    }

    // Epilogue: y1 for row h0+7 needs gy at row h0+8 (rows h0+7 and h0+9).
    const int hl = h0 + 7;
    if (hl < 1023) {
        double* B0 = r[8 % 3];           // row h0+7 (see rotation: r[2])
        double bn[7];
        load_row(xb, hl + 2, t, bn);     // row h0+9 (clamped/zeroed if OOB)
        double d2[6];
        #pragma unroll
        for (int c = 0; c < 6; ++c) d2[c] = B0[c] - bn[c];
        size_t p = Y1 + (size_t)hl * 1023u + (size_t)w0;
        #pragma unroll
        for (int j = 0; j < 4; ++j) {
            double gyn = d2[j] + 2.0 * d2[j + 1] + d2[j + 2];  // gy(h0+8, w0+j)
            if (w0 + j < 1023) out[p + j] = psgy[j] - fsign(gyn);
        }
    }
}

extern "C" void kernel_launch(void* const* d_in, const int* in_sizes, int n_in,
                              void* d_out, int out_size, void* d_ws, size_t ws_size,
                              hipStream_t stream) {
    const float* x = (const float*)d_in[0];
    float* out = (float*)d_out;
    dim3 grid(16 * 128), block(256);   // one block per (b, 8-row group)
    sobel_sign_kernel<<<grid, block, 0, stream>>>(x, out);
}

// Round 5
// 318.622 us; speedup vs baseline: 1.4200x; 1.1132x over previous
//
#include <hip/hip_runtime.h>

// Sobel conv (cross-correlation, zero-pad SAME) + sign-difference maps.
// x: [16,1,1024,1024] f32 -> y: [16,2,1024,1024], y0,y1: [16,1,1023,1023]
// Outputs concatenated flat in d_out (float32).
//
// f64 accumulation (weights {1,2} exact -> sign() matches high-precision ref;
// passed rounds 1-3, numerics unchanged).
//
// Round-4 changes (resubmitted after infra failure):
//  * y0/y1 stores go through a 4KB LDS transpose so every wave store is
//    lane-contiguous dwords (round 2/3 had 16B-strided scalar stores).
//  * software prefetch: raw float4s for row h+2 are issued before computing
//    row h, hiding load latency under the f64 math.

__device__ __forceinline__ void load_raw(const float* __restrict__ xb, int r, int t,
                                         float4& L, float4& C, float4& R) {
    if ((unsigned)r < 1024u) {                       // uniform branch (r is block-uniform)
        const float4* __restrict__ rp = (const float4*)(xb + (r << 10));
        L = rp[(t > 0) ? (t - 1) : 0];
        C = rp[t];
        R = rp[(t < 255) ? (t + 1) : 255];
    } else {
        L = C = R = make_float4(0.f, 0.f, 0.f, 0.f);  // zero-pad rows
    }
}

__device__ __forceinline__ void cvt_row(float4 L, float4 C, float4 R, int t,
                                        double* __restrict__ o /*[7]*/) {
    float lw = (t > 0)   ? L.w : 0.f;   // col w0-1 (zero-pad col -1)
    float r0 = (t < 255) ? R.x : 0.f;   // col w0+4 (zero-pad col 1024)
    float r1 = (t < 255) ? R.y : 0.f;   // col w0+5
    o[0] = (double)lw;  o[1] = (double)C.x; o[2] = (double)C.y; o[3] = (double)C.z;
    o[4] = (double)C.w; o[5] = (double)r0;  o[6] = (double)r1;
}

__device__ __forceinline__ float fsign(double v) {
    return (v > 0.0) ? 1.0f : ((v < 0.0) ? -1.0f : 0.0f);
}

__global__ __launch_bounds__(256) void sobel_sign_kernel(const float* __restrict__ x,
                                                         float* __restrict__ out) {
    const int t  = threadIdx.x;          // 0..255 -> cols 4t..4t+3
    const int b  = blockIdx.x >> 7;      // image
    const int hg = blockIdx.x & 127;     // 8-row group
    const int h0 = hg << 3;
    const int w0 = t << 2;

    const float* __restrict__ xb = x + ((size_t)b << 20);
    float* __restrict__ yb = out + ((size_t)b << 21);
    const size_t NP = (size_t)1023 * 1023;                 // 1046529
    float* __restrict__ Y0 = out + 33554432u + (size_t)b * NP;
    float* __restrict__ Y1 = out + 50298896u + (size_t)b * NP;

    __shared__ float s0[1024];
    __shared__ float s1[1024];

    double r[3][7];                      // rolling f64 rows
    float4 L, C, R;                      // raw prefetch regs
    load_raw(xb, h0 - 1, t, L, C, R); cvt_row(L, C, R, t, r[0]);
    load_raw(xb, h0,     t, L, C, R); cvt_row(L, C, R, t, r[1]);
    load_raw(xb, h0 + 1, t, L, C, R);    // raw holds row h0+1

    float psgy[4];                       // sign(gy) of previous row

    #pragma unroll
    for (int it = 0; it < 8; ++it) {
        const int h = h0 + it;
        double* A0 = r[it % 3];          // row h-1
        double* A1 = r[(it + 1) % 3];    // row h
        double* A2 = r[(it + 2) % 3];    // row h+1
        cvt_row(L, C, R, t, A2);         // raw (row h+1) -> f64 window
        load_raw(xb, h + 2, t, L, C, R); // prefetch row h+2 (it==7 -> h0+9, used by epilogue)

        double tc[7], d[6];
        #pragma unroll
        for (int c = 0; c < 7; ++c) tc[c] = A0[c] + 2.0 * A1[c] + A2[c];
        #pragma unroll
        for (int c = 0; c < 6; ++c) d[c] = A0[c] - A2[c];

        double gx[5], gy[4];
        #pragma unroll
        for (int j = 0; j < 5; ++j) gx[j] = tc[j] - tc[j + 2];       // gx(h, w0+j)
        #pragma unroll
        for (int j = 0; j < 4; ++j) gy[j] = d[j] + 2.0 * d[j + 1] + d[j + 2];

        // y stores: [b, ch, h, w], float4-aligned, lane-contiguous
        size_t yo = ((size_t)h << 10) + (size_t)w0;
        *(float4*)(yb + yo) =
            make_float4((float)gx[0], (float)gx[1], (float)gx[2], (float)gx[3]);
        *(float4*)(yb + yo + (1u << 20)) =
            make_float4((float)gy[0], (float)gy[1], (float)gy[2], (float)gy[3]);

        float sgx[5], sgy[4];
        #pragma unroll
        for (int j = 0; j < 5; ++j) sgx[j] = fsign(gx[j]);
        #pragma unroll
        for (int j = 0; j < 4; ++j) sgy[j] = fsign(gy[j]);

        // Stage y0 (row h) and y1 (row h-1) in LDS, then store lane-contiguous.
        __syncthreads();                 // protect previous iteration's reads
        #pragma unroll
        for (int j = 0; j < 4; ++j) {
            s0[w0 + j] = sgx[j] - sgx[j + 1];
            s1[w0 + j] = (it > 0) ? (psgy[j] - sgy[j]) : 0.f;
        }
        __syncthreads();
        #pragma unroll
        for (int k = 0; k < 4; ++k) {
            int c = t + (k << 8);
            bool cok = c < 1023;         // only lane t=255,k=3 masked
            if (h < 1023 && cok) Y0[(size_t)h * 1023u + c] = s0[c];
            if (it > 0 && cok)   Y1[(size_t)(h - 1) * 1023u + c] = s1[c];
        }
        #pragma unroll
        for (int j = 0; j < 4; ++j) psgy[j] = sgy[j];
    }

    // Epilogue: y1 for row hl=h0+7 needs gy(h0+8) from rows h0+7 (window r[2])
    // and h0+9 (raw regs).
    {
        const int hl = h0 + 7;
        double bn[7];
        cvt_row(L, C, R, t, bn);         // row h0+9
        double* B0 = r[2];               // row h0+7
        float y1v[4];
        #pragma unroll
        for (int j = 0; j < 4; ++j) {
            double d0 = B0[j]     - bn[j];
            double d1 = B0[j + 1] - bn[j + 1];
            double d2 = B0[j + 2] - bn[j + 2];
            double gyn = d0 + 2.0 * d1 + d2;         // gy(h0+8, w0+j)
            y1v[j] = psgy[j] - fsign(gyn);
        }
        __syncthreads();
        #pragma unroll
        for (int j = 0; j < 4; ++j) s1[w0 + j] = y1v[j];
        __syncthreads();
        if (hl < 1023) {                 // uniform; false only for hg==127
            #pragma unroll
            for (int k = 0; k < 4; ++k) {
                int c = t + (k << 8);
                if (c < 1023) Y1[(size_t)hl * 1023u + c] = s1[c];
            }
        }
    }
}

extern "C" void kernel_launch(void* const* d_in, const int* in_sizes, int n_in,
                              void* d_out, int out_size, void* d_ws, size_t ws_size,
                              hipStream_t stream) {
    const float* x = (const float*)d_in[0];
    float* out = (float*)d_out;
    dim3 grid(16 * 128), block(256);   // one block per (b, 8-row group)
    sobel_sign_kernel<<<grid, block, 0, stream>>>(x, out);
}